// Round 3
// baseline (421.277 us; speedup 1.0000x reference)
//
#include <hip/hip_runtime.h>

#define BDIM 8
#define CDIM 256
#define HDIM 96
#define WDIM 96
#define GRP  4
#define CG   64          // channels per group
#define HC   32          // channels per sample-block (half group)
#define SH   192         // s*H
#define SW   192         // s*W
#define HW   (HDIM*WDIM) // 9216

// ---------------------------------------------------------------------------
// Kernel 1: per-pixel 256->32 dot product (the 1x1 conv offset head).
// K-split by 4: block = 256 threads = 64 pixels x 4 channel-slices.
// Round-3 change: explicit 16-deep x-load pipeline. Previously unroll-4 left
// only 4 HBM loads in flight per thread (x is L3-cold: the harness re-poison
// fill flushes 1.2 GB through L3 every iteration), so waves sat ~90% idle on
// vmcnt. Now: 16 loads (registers) -> 512 FMAs per group; compute (1024 cyc)
// covers miss latency (~900 cyc) even per-wave, x4 waves/SIMD.
// w_off reads are wave-uniform (ks via readfirstlane) -> s_load path.
// ---------------------------------------------------------------------------
__global__ __launch_bounds__(256) void dysample_offset_kernel(
    const float* __restrict__ x,
    const float* __restrict__ w_off,
    const float* __restrict__ b_off,
    float* __restrict__ off)
{
    __shared__ float part[4][64][33];

    int tid = threadIdx.x;
    int pix = tid & 63;
    int ks  = __builtin_amdgcn_readfirstlane(tid >> 6);

    int p0  = blockIdx.x * 64;
    int b0  = p0 / HW;
    int hw0 = p0 - b0 * HW;
    int hw  = hw0 + pix;

    const float* xq = x + (size_t)b0 * CDIM * HW + (size_t)(ks * CG) * HW + hw;
    const float* wq = w_off + ks * CG;

    float acc[32];
    #pragma unroll
    for (int o = 0; o < 32; ++o) acc[o] = 0.0f;

    #pragma unroll 1
    for (int i0 = 0; i0 < CG; i0 += 16) {
        float xv[16];
        #pragma unroll
        for (int u = 0; u < 16; ++u)
            xv[u] = xq[(size_t)(i0 + u) * HW];      // 16 loads in flight
        #pragma unroll
        for (int u = 0; u < 16; ++u) {
            #pragma unroll
            for (int o = 0; o < 32; ++o)
                acc[o] = fmaf(xv[u], wq[o * CDIM + (i0 + u)], acc[o]);
        }
    }

    #pragma unroll
    for (int o = 0; o < 32; ++o)
        part[ks][pix][o] = acc[o];

    __syncthreads();

    int pix2 = tid & 63;
    int og   = tid >> 6;
    float* op = off + ((size_t)b0 * 32) * HW + hw0 + pix2;
    #pragma unroll
    for (int j = 0; j < 8; ++j) {
        int o = og * 8 + j;
        float s = part[0][pix2][o] + part[1][pix2][o]
                + part[2][pix2][o] + part[3][pix2][o];
        op[(size_t)o * HW] = (s + b_off[o]) * 0.25f;
    }
}

// ---------------------------------------------------------------------------
// Kernel 2: bilinear sampling, LDS-staged. (unchanged from round 2)
// Block = 768 threads = one (b, gi, hc, ht): 4 output rows x 192 cols x 32 ch.
// ---------------------------------------------------------------------------
#define NBLK2 (BDIM * GRP * 2 * 48)   // 3072; % 8 == 0 -> simple swizzle ok
__global__ __launch_bounds__(768, 1) void dysample_sample_kernel(
    const float* __restrict__ x,
    const float* __restrict__ off,
    float* __restrict__ out)
{
    __shared__ __align__(16) float lds[HC * 384 + 4];   // 49 168 B

    int lid = (blockIdx.x & 7) * (NBLK2 / 8) + (blockIdx.x >> 3);
    int ht  = lid % 48;
    int t1  = lid / 48;
    int hc  = t1 & 1;
    int t2  = t1 >> 1;
    int gi  = t2 & 3;
    int b   = t2 >> 2;

    int tid = threadIdx.x;
    int ylo = 2 * ht - 1;

    const float* xg = x + ((size_t)b * CDIM + gi * CG + hc * HC) * HW;
    float4 tmp[4];
    #pragma unroll
    for (int k = 0; k < 4; ++k) {
        int c   = tid + k * 768;
        int ch  = c / 96;
        int r96 = c - ch * 96;
        int j   = r96 / 24;
        int q   = r96 - j * 24;
        int ysrc = min(max(ylo + j, 0), HDIM - 1);
        tmp[k] = *(const float4*)(xg + (size_t)ch * HW + ysrc * WDIM + q * 4);
    }
    #pragma unroll
    for (int k = 0; k < 4; ++k) {
        int c = tid + k * 768;
        *(float4*)(&lds[c * 4]) = tmp[k];
    }
    __syncthreads();

    int cc = tid % 192;
    int rl = tid / 192;
    int r  = ht * 4 + rl;

    int h  = r >> 1, s1 = r & 1;
    int w  = cc >> 1, s2 = cc & 1;
    int o16 = gi * 4 + s1 * 2 + s2;

    size_t obase = ((size_t)b * 32 + o16) * HW + (size_t)h * WDIM + w;
    float ox = off[obase];
    float oy = off[obase + (size_t)16 * HW];

    float ix = fminf(fmaxf((float)w + ox, 0.0f), (float)(WDIM - 1));
    float iy = fminf(fmaxf((float)h + oy, 0.0f), (float)(HDIM - 1));
    float x0f = floorf(ix), y0f = floorf(iy);
    float wx = ix - x0f,   wy = iy - y0f;
    int x0 = (int)x0f, y0 = (int)y0f;
    int y1 = min(y0 + 1, HDIM - 1);

    float w00 = (1.0f - wy) * (1.0f - wx);
    float w01 = (1.0f - wy) * wx;
    float w10 = wy * (1.0f - wx);
    float w11 = wy * wx;

    int i0 = y0 - ylo;
    int i1 = y1 - ylo;

    float* op = out + (((size_t)b * CDIM + gi * CG + hc * HC) * SH + r) * SW + cc;

    if (i0 >= 0 && i1 <= 3) {
        int a0 = i0 * WDIM + x0;
        int a1 = i1 * WDIM + x0;
        #pragma unroll 8
        for (int ch = 0; ch < HC; ++ch) {
            const float* p = &lds[ch * 384];
            float v = p[a0] * w00;
            v = fmaf(p[a0 + 1], w01, v);
            v = fmaf(p[a1],     w10, v);
            v = fmaf(p[a1 + 1], w11, v);
            __builtin_nontemporal_store(v, op + (size_t)ch * (SH * SW));
        }
    } else {
        int x1 = min(x0 + 1, WDIM - 1);
        int i00 = y0 * WDIM + x0, i01 = y0 * WDIM + x1;
        int i10 = y1 * WDIM + x0, i11 = y1 * WDIM + x1;
        #pragma unroll 4
        for (int ch = 0; ch < HC; ++ch) {
            const float* p = xg + (size_t)ch * HW;
            float v = p[i00] * w00 + p[i01] * w01 + p[i10] * w10 + p[i11] * w11;
            __builtin_nontemporal_store(v, op + (size_t)ch * (SH * SW));
        }
    }
}

extern "C" void kernel_launch(void* const* d_in, const int* in_sizes, int n_in,
                              void* d_out, int out_size, void* d_ws, size_t ws_size,
                              hipStream_t stream)
{
    const float* x     = (const float*)d_in[0];
    const float* w_off = (const float*)d_in[1];
    const float* b_off = (const float*)d_in[2];
    float* out = (float*)d_out;
    float* off = (float*)d_ws;   // needs 8*32*96*96*4 = 9.44 MB

    // Kernel 1: 73728 pixels / 64 px-per-block = 1152 blocks x 256 threads
    dysample_offset_kernel<<<(BDIM * HW) / 64, 256, 0, stream>>>(x, w_off, b_off, off);

    // Kernel 2: 3072 blocks x 768 threads (4 rows x 192 cols x 32 ch)
    dysample_sample_kernel<<<NBLK2, 768, 0, stream>>>(x, off, out);
}

// Round 4
// 368.388 us; speedup vs baseline: 1.1436x; 1.1436x over previous
//
#include <hip/hip_runtime.h>

#define BDIM 8
#define CDIM 256
#define HDIM 96
#define WDIM 96
#define GRP  4
#define CG   64          // channels per group
#define HC   32          // channels per sample-block (half group)
#define SH   192         // s*H
#define SW   192         // s*W
#define HW   (HDIM*WDIM) // 9216

// ---------------------------------------------------------------------------
// Kernel 1: per-pixel 256->32 dot product (the 1x1 conv offset head).
// Round-4 change: weights delivered via LDS broadcast, not the scalar path.
// Rounds 0-3 fed w_off through s_loads; the FMA chain needs 32 uniform
// weights per channel and the SGPR file can't hold enough ahead, so the
// compiler serialized on lgkmcnt (offset kernel ~149 us vs ~12 us roofline).
// Now: stage w_off TRANSPOSED into LDS once per block (wT[c][o], 32 KB);
// inner loop per channel = 1 pipelined global x-load + 8 ds_read_b128
// (same-address broadcast, conflict-free) + 32 FMAs. K-split by 4 waves as
// before, LDS tree-combine. 66.5 KB LDS -> 2 blocks/CU = 8 waves/SIMD.
// ---------------------------------------------------------------------------
__global__ __launch_bounds__(256) void dysample_offset_kernel(
    const float* __restrict__ x,
    const float* __restrict__ w_off,
    const float* __restrict__ b_off,
    float* __restrict__ off)
{
    __shared__ __align__(16) float wT[CDIM][32];   // 32 KB, [c][o]
    __shared__ float part[4][64][33];              // 33.8 KB, pad -> no conflicts

    int tid = threadIdx.x;

    // ---- stage w_off transposed: thread t -> o = t&31, c-chunk = t>>5 ----
    {
        int o  = tid & 31;
        int cb = (tid >> 5) * 32;      // 8 chunks of 32 cover c = 0..255
        #pragma unroll 8
        for (int j = 0; j < 32; ++j) {
            // column read: uncoalesced but one-time & L2-resident (32 KB)
            wT[cb + j][o] = w_off[o * CDIM + cb + j];
            // ds_write banks: (c*32+o)%32 == o -> 2 lanes/bank distinct addr: free
        }
    }
    __syncthreads();

    int pix = tid & 63;
    int ks  = __builtin_amdgcn_readfirstlane(tid >> 6);

    int p0  = blockIdx.x * 64;          // 64 | HW -> block never straddles b
    int b0  = p0 / HW;
    int hw0 = p0 - b0 * HW;
    int hw  = hw0 + pix;

    const float* xq = x + (size_t)b0 * CDIM * HW + (size_t)(ks * CG) * HW + hw;

    float acc[32];
    #pragma unroll
    for (int o = 0; o < 32; ++o) acc[o] = 0.0f;

    // ---- main loop: groups of 8 channels, double-buffered x loads ----
    float xa[8], xb[8];
    #pragma unroll
    for (int u = 0; u < 8; ++u) xa[u] = xq[(size_t)u * HW];

    #pragma unroll 1
    for (int g = 0; g < 8; ++g) {
        // issue next group's loads first (8 in flight under the FMAs)
        if (g < 7) {
            #pragma unroll
            for (int u = 0; u < 8; ++u)
                xb[u] = xq[(size_t)((g + 1) * 8 + u) * HW];
        }
        #pragma unroll
        for (int u = 0; u < 8; ++u) {
            int c = ks * CG + g * 8 + u;
            float xv = xa[u];
            #pragma unroll
            for (int o4 = 0; o4 < 8; ++o4) {
                // all 64 lanes read the same address -> LDS broadcast
                const float4 wv = *(const float4*)&wT[c][o4 * 4];
                acc[o4 * 4 + 0] = fmaf(xv, wv.x, acc[o4 * 4 + 0]);
                acc[o4 * 4 + 1] = fmaf(xv, wv.y, acc[o4 * 4 + 1]);
                acc[o4 * 4 + 2] = fmaf(xv, wv.z, acc[o4 * 4 + 2]);
                acc[o4 * 4 + 3] = fmaf(xv, wv.w, acc[o4 * 4 + 3]);
            }
        }
        #pragma unroll
        for (int u = 0; u < 8; ++u) xa[u] = xb[u];
    }

    #pragma unroll
    for (int o = 0; o < 32; ++o)
        part[ks][pix][o] = acc[o];

    __syncthreads();

    int pix2 = tid & 63;
    int og   = tid >> 6;
    float* op = off + ((size_t)b0 * 32) * HW + hw0 + pix2;
    #pragma unroll
    for (int j = 0; j < 8; ++j) {
        int o = og * 8 + j;
        float s = part[0][pix2][o] + part[1][pix2][o]
                + part[2][pix2][o] + part[3][pix2][o];
        op[(size_t)o * HW] = (s + b_off[o]) * 0.25f;
    }
}

// ---------------------------------------------------------------------------
// Kernel 2: bilinear sampling, LDS-staged. (unchanged from round 2)
// Block = 768 threads = one (b, gi, hc, ht): 4 output rows x 192 cols x 32 ch.
// ---------------------------------------------------------------------------
#define NBLK2 (BDIM * GRP * 2 * 48)   // 3072; % 8 == 0 -> simple swizzle ok
__global__ __launch_bounds__(768, 1) void dysample_sample_kernel(
    const float* __restrict__ x,
    const float* __restrict__ off,
    float* __restrict__ out)
{
    __shared__ __align__(16) float lds[HC * 384 + 4];   // 49 168 B

    int lid = (blockIdx.x & 7) * (NBLK2 / 8) + (blockIdx.x >> 3);
    int ht  = lid % 48;
    int t1  = lid / 48;
    int hc  = t1 & 1;
    int t2  = t1 >> 1;
    int gi  = t2 & 3;
    int b   = t2 >> 2;

    int tid = threadIdx.x;
    int ylo = 2 * ht - 1;

    const float* xg = x + ((size_t)b * CDIM + gi * CG + hc * HC) * HW;
    float4 tmp[4];
    #pragma unroll
    for (int k = 0; k < 4; ++k) {
        int c   = tid + k * 768;
        int ch  = c / 96;
        int r96 = c - ch * 96;
        int j   = r96 / 24;
        int q   = r96 - j * 24;
        int ysrc = min(max(ylo + j, 0), HDIM - 1);
        tmp[k] = *(const float4*)(xg + (size_t)ch * HW + ysrc * WDIM + q * 4);
    }
    #pragma unroll
    for (int k = 0; k < 4; ++k) {
        int c = tid + k * 768;
        *(float4*)(&lds[c * 4]) = tmp[k];
    }
    __syncthreads();

    int cc = tid % 192;
    int rl = tid / 192;
    int r  = ht * 4 + rl;

    int h  = r >> 1, s1 = r & 1;
    int w  = cc >> 1, s2 = cc & 1;
    int o16 = gi * 4 + s1 * 2 + s2;

    size_t obase = ((size_t)b * 32 + o16) * HW + (size_t)h * WDIM + w;
    float ox = off[obase];
    float oy = off[obase + (size_t)16 * HW];

    float ix = fminf(fmaxf((float)w + ox, 0.0f), (float)(WDIM - 1));
    float iy = fminf(fmaxf((float)h + oy, 0.0f), (float)(HDIM - 1));
    float x0f = floorf(ix), y0f = floorf(iy);
    float wx = ix - x0f,   wy = iy - y0f;
    int x0 = (int)x0f, y0 = (int)y0f;
    int y1 = min(y0 + 1, HDIM - 1);

    float w00 = (1.0f - wy) * (1.0f - wx);
    float w01 = (1.0f - wy) * wx;
    float w10 = wy * (1.0f - wx);
    float w11 = wy * wx;

    int i0 = y0 - ylo;
    int i1 = y1 - ylo;

    float* op = out + (((size_t)b * CDIM + gi * CG + hc * HC) * SH + r) * SW + cc;

    if (i0 >= 0 && i1 <= 3) {
        int a0 = i0 * WDIM + x0;
        int a1 = i1 * WDIM + x0;
        #pragma unroll 8
        for (int ch = 0; ch < HC; ++ch) {
            const float* p = &lds[ch * 384];
            float v = p[a0] * w00;
            v = fmaf(p[a0 + 1], w01, v);
            v = fmaf(p[a1],     w10, v);
            v = fmaf(p[a1 + 1], w11, v);
            __builtin_nontemporal_store(v, op + (size_t)ch * (SH * SW));
        }
    } else {
        int x1 = min(x0 + 1, WDIM - 1);
        int i00 = y0 * WDIM + x0, i01 = y0 * WDIM + x1;
        int i10 = y1 * WDIM + x0, i11 = y1 * WDIM + x1;
        #pragma unroll 4
        for (int ch = 0; ch < HC; ++ch) {
            const float* p = xg + (size_t)ch * HW;
            float v = p[i00] * w00 + p[i01] * w01 + p[i10] * w10 + p[i11] * w11;
            __builtin_nontemporal_store(v, op + (size_t)ch * (SH * SW));
        }
    }
}

extern "C" void kernel_launch(void* const* d_in, const int* in_sizes, int n_in,
                              void* d_out, int out_size, void* d_ws, size_t ws_size,
                              hipStream_t stream)
{
    const float* x     = (const float*)d_in[0];
    const float* w_off = (const float*)d_in[1];
    const float* b_off = (const float*)d_in[2];
    float* out = (float*)d_out;
    float* off = (float*)d_ws;   // needs 8*32*96*96*4 = 9.44 MB

    // Kernel 1: 73728 pixels / 64 px-per-block = 1152 blocks x 256 threads
    dysample_offset_kernel<<<(BDIM * HW) / 64, 256, 0, stream>>>(x, w_off, b_off, off);

    // Kernel 2: 3072 blocks x 768 threads (4 rows x 192 cols x 32 ch)
    dysample_sample_kernel<<<NBLK2, 768, 0, stream>>>(x, off, out);
}